// Round 1
// 344.953 us; speedup vs baseline: 1.0165x; 1.0165x over previous
//
#include <hip/hip_runtime.h>

#define N_NODES 50000
#define N_EDGES 800000
#define IN_F    512
#define NH      4
#define DH      64
#define HD      256   // NH*DH
#define NEG     0.2f
#define NB      ((N_NODES + 255) / 256)   // 196 scan blocks

typedef __attribute__((ext_vector_type(8))) short bf16x8;
typedef __attribute__((ext_vector_type(4))) float f32x4;

__device__ __forceinline__ unsigned short f2bf(float x) {
    unsigned u = __float_as_uint(x);
    unsigned r = (u + 0x7FFFu + ((u >> 16) & 1u)) >> 16;  // RNE
    return (unsigned short)r;
}
__device__ __forceinline__ float bf2f(unsigned short b) {
    return __uint_as_float((unsigned)b << 16);
}

// ---------------- setup: zero counts (blocks 0..NB-1) + W->Wt bf16 (rest) ----
__global__ __launch_bounds__(256) void setup_kernel(const float* __restrict__ W,
                                                    unsigned short* __restrict__ Wtb,
                                                    int* __restrict__ counts) {
    int b = blockIdx.x;
    if (b < NB) {
        int i = b * 256 + threadIdx.x;
        if (i < N_NODES) counts[i] = 0;
    } else {
        int i = (b - NB) * 256 + threadIdx.x;   // over 512*256
        if (i < IN_F * HD) {
            int k = i >> 8;        // 0..511
            int n = i & 255;       // 0..255
            Wtb[(size_t)n * IN_F + k] = f2bf(W[i]);
        }
    }
}

// ---------------- per-dst edge counts ----------------
__global__ __launch_bounds__(256) void count_kernel(const int* __restrict__ dst,
                                                    int* __restrict__ counts) {
    int e = blockIdx.x * blockDim.x + threadIdx.x;
    if (e < N_EDGES) atomicAdd(&counts[dst[e]], 1);
}

// ---------------- bf16 MFMA GEMM: ftb = bf16(feat @ W), el/er fused -----------
// 64x256 tile (single column block: feat read from HBM exactly once), BK=64,
// 4 waves, wave w owns cols [w*64, w*64+64) == head w. acc[4][4] per wave.
// Register-prefetch pipeline: tile k+1's global loads issue right after the
// store barrier, overlapping compute of tile k. 782 blocks, 3 blocks/CU (LDS).
// Epilogue computes el/er from the fp32 accumulators (wave==head), removing
// the separate el_er kernel and its 25.6 MB ftb re-read.
#define LDPA 72   // padded LDS row stride in shorts
#define LDPB 72
__global__ __launch_bounds__(256) void gemm_kernel(const float* __restrict__ A,
                                                   const unsigned short* __restrict__ Wtb,
                                                   const float* __restrict__ attn_l,
                                                   const float* __restrict__ attn_r,
                                                   unsigned short* __restrict__ Cb,
                                                   float* __restrict__ el,
                                                   float* __restrict__ er) {
    __shared__ short A_s[64][LDPA];     // 9.2 KB
    __shared__ short B_s[256][LDPB];    // 36.9 KB

    const int tid  = threadIdx.x;
    const int lane = tid & 63;
    const int w    = tid >> 6;      // wave id == head id == col block
    const int lm   = lane & 15;
    const int quad = lane >> 4;
    const int row0 = blockIdx.x * 64;

    // staging: unit = 8 contiguous elems; A 64x64 fp32 (16 floats/thr),
    // B 256x64 bf16 (8 units of 32 rows)
    const int srow = tid >> 3;          // 0..31
    const int sc8  = (tid & 7) * 8;

    f32x4 acc[4][4] = {};
    float4 pa[4];
    bf16x8 pb[8];

#define LOAD_TILES(KT)                                                         \
    {                                                                          \
        int g0 = row0 + srow;                                                  \
        if (g0 < N_NODES) {                                                    \
            const float* ap = A + (size_t)g0 * IN_F + (KT) + sc8;              \
            pa[0] = *(const float4*)ap; pa[1] = *(const float4*)(ap + 4);      \
        } else { pa[0] = pa[1] = make_float4(0.f, 0.f, 0.f, 0.f); }            \
        int g1 = row0 + 32 + srow;                                             \
        if (g1 < N_NODES) {                                                    \
            const float* ap = A + (size_t)g1 * IN_F + (KT) + sc8;              \
            pa[2] = *(const float4*)ap; pa[3] = *(const float4*)(ap + 4);      \
        } else { pa[2] = pa[3] = make_float4(0.f, 0.f, 0.f, 0.f); }            \
        _Pragma("unroll")                                                      \
        for (int it = 0; it < 8; it++) {                                       \
            int brow = it * 32 + srow;                                         \
            pb[it] = *(const bf16x8*)(Wtb + (size_t)brow * IN_F +              \
                                      (KT) + sc8);                             \
        }                                                                      \
    }

    LOAD_TILES(0);

    for (int kt = 0; kt < IN_F; kt += 64) {
        // convert + store current prefetched tile to LDS (vmcnt wait lands here)
        {
            bf16x8 s;
            s[0] = (short)f2bf(pa[0].x); s[1] = (short)f2bf(pa[0].y);
            s[2] = (short)f2bf(pa[0].z); s[3] = (short)f2bf(pa[0].w);
            s[4] = (short)f2bf(pa[1].x); s[5] = (short)f2bf(pa[1].y);
            s[6] = (short)f2bf(pa[1].z); s[7] = (short)f2bf(pa[1].w);
            *(bf16x8*)(&A_s[srow][sc8]) = s;
            s[0] = (short)f2bf(pa[2].x); s[1] = (short)f2bf(pa[2].y);
            s[2] = (short)f2bf(pa[2].z); s[3] = (short)f2bf(pa[2].w);
            s[4] = (short)f2bf(pa[3].x); s[5] = (short)f2bf(pa[3].y);
            s[6] = (short)f2bf(pa[3].z); s[7] = (short)f2bf(pa[3].w);
            *(bf16x8*)(&A_s[32 + srow][sc8]) = s;
#pragma unroll
            for (int it = 0; it < 8; it++)
                *(bf16x8*)(&B_s[it * 32 + srow][sc8]) = pb[it];
        }
        __syncthreads();

        // issue next tile's global loads (overlap with compute below)
        if (kt + 64 < IN_F) LOAD_TILES(kt + 64);

        // compute current tile from LDS
#pragma unroll
        for (int kk = 0; kk < 64; kk += 32) {
            bf16x8 af[4], bfr[4];
#pragma unroll
            for (int i = 0; i < 4; i++)
                af[i] = *(const bf16x8*)(&A_s[i * 16 + lm][kk + quad * 8]);
#pragma unroll
            for (int j = 0; j < 4; j++)
                bfr[j] = *(const bf16x8*)(&B_s[w * 64 + j * 16 + lm][kk + quad * 8]);
#pragma unroll
            for (int i = 0; i < 4; i++)
#pragma unroll
                for (int j = 0; j < 4; j++)
                    acc[i][j] = __builtin_amdgcn_mfma_f32_16x16x32_bf16(
                        af[i], bfr[j], acc[i][j], 0, 0, 0);
        }
        __syncthreads();   // protect LDS before next iteration's store
    }
#undef LOAD_TILES

    // C/D layout: col = lane&15, row = quad*4 + reg; store bf16
#pragma unroll
    for (int i = 0; i < 4; i++) {
#pragma unroll
        for (int j = 0; j < 4; j++) {
            int gcol = w * 64 + j * 16 + lm;
#pragma unroll
            for (int r = 0; r < 4; r++) {
                int grow = row0 + i * 16 + quad * 4 + r;
                if (grow < N_NODES)
                    Cb[(size_t)grow * HD + gcol] = f2bf(acc[i][j][r]);
            }
        }
    }

    // fused el/er: wave w == head w; each row's 64 cols live in 16 lanes of one
    // quad (regs over i,j,r). 4-fma per lane + 16-lane shfl_xor reduce.
    {
        float al[4], ar[4];
#pragma unroll
        for (int j = 0; j < 4; j++) {
            al[j] = attn_l[w * DH + j * 16 + lm];
            ar[j] = attn_r[w * DH + j * 16 + lm];
        }
#pragma unroll
        for (int i = 0; i < 4; i++) {
#pragma unroll
            for (int r = 0; r < 4; r++) {
                float sl = 0.f, sr = 0.f;
#pragma unroll
                for (int j = 0; j < 4; j++) {
                    sl += acc[i][j][r] * al[j];
                    sr += acc[i][j][r] * ar[j];
                }
#pragma unroll
                for (int off = 8; off > 0; off >>= 1) {
                    sl += __shfl_xor(sl, off);
                    sr += __shfl_xor(sr, off);
                }
                if (lm == 0) {
                    int grow = row0 + i * 16 + quad * 4 + r;
                    if (grow < N_NODES) {
                        el[(size_t)grow * NH + w] = sl;
                        er[(size_t)grow * NH + w] = sr;
                    }
                }
            }
        }
    }
}

// ---------------- 3-phase parallel exclusive scan of counts -------------------
__global__ __launch_bounds__(256) void partial_kernel(const int* __restrict__ counts,
                                                      int* __restrict__ bsums) {
    __shared__ int red[4];
    int i = blockIdx.x * 256 + threadIdx.x;
    int c = (i < N_NODES) ? counts[i] : 0;
#pragma unroll
    for (int off = 32; off > 0; off >>= 1) c += __shfl_down(c, off);
    if ((threadIdx.x & 63) == 0) red[threadIdx.x >> 6] = c;
    __syncthreads();
    if (threadIdx.x == 0) bsums[blockIdx.x] = red[0] + red[1] + red[2] + red[3];
}

__global__ __launch_bounds__(256) void bscan_kernel(const int* __restrict__ bsums,
                                                    int* __restrict__ boffs) {
    __shared__ int s[256];
    int tid = threadIdx.x;
    s[tid] = (tid < NB) ? bsums[tid] : 0;
    __syncthreads();
    for (int off = 1; off < 256; off <<= 1) {
        int x = s[tid];
        int a = (tid >= off) ? s[tid - off] : 0;
        __syncthreads();
        s[tid] = x + a;
        __syncthreads();
    }
    if (tid < NB) boffs[tid] = (tid > 0) ? s[tid - 1] : 0;
}

__global__ __launch_bounds__(256) void scatter_scan_kernel(const int* __restrict__ counts,
                                                           const int* __restrict__ boffs,
                                                           int* __restrict__ offsets,
                                                           int* __restrict__ cursor) {
    __shared__ int s[256];
    int tid = threadIdx.x;
    int i = blockIdx.x * 256 + tid;
    s[tid] = (i < N_NODES) ? counts[i] : 0;
    __syncthreads();
    for (int off = 1; off < 256; off <<= 1) {
        int x = s[tid];
        int a = (tid >= off) ? s[tid - off] : 0;
        __syncthreads();
        s[tid] = x + a;
        __syncthreads();
    }
    int excl = (tid > 0) ? s[tid - 1] : 0;
    int o = boffs[blockIdx.x] + excl;
    if (i < N_NODES) { offsets[i] = o; cursor[i] = o; }
    if (i == 0) offsets[N_NODES] = N_EDGES;
}

// ---------------- edge scores placed directly in CSR order --------------------
__device__ __forceinline__ float lrelu_exp(float x) {
    float y = (x > 0.f) ? x : NEG * x;
    return __expf(y);
}

__global__ __launch_bounds__(256) void edge_place_kernel(const int* __restrict__ src,
                                                         const int* __restrict__ dst,
                                                         const float* __restrict__ el,
                                                         const float* __restrict__ er,
                                                         int* __restrict__ cursor,
                                                         int* __restrict__ srcs,
                                                         float* __restrict__ w4s) {
    int e = blockIdx.x * blockDim.x + threadIdx.x;
    if (e >= N_EDGES) return;
    int u = src[e], v = dst[e];
    float4 l = *(const float4*)(el + (size_t)u * NH);
    float4 r = *(const float4*)(er + (size_t)v * NH);
    float4 s;
    s.x = lrelu_exp(l.x + r.x);
    s.y = lrelu_exp(l.y + r.y);
    s.z = lrelu_exp(l.z + r.z);
    s.w = lrelu_exp(l.w + r.w);
    int pos = atomicAdd(&cursor[v], 1);
    srcs[pos] = u;
    *(float4*)(w4s + (size_t)pos * NH) = s;
}

// ---------------- aggregation: one wave per dst, 4-edge software pipeline -----
__global__ __launch_bounds__(256) void agg_kernel(const unsigned short* __restrict__ ftb,
                                                  const float* __restrict__ w4s,
                                                  const int* __restrict__ srcs,
                                                  const int* __restrict__ offsets,
                                                  float* __restrict__ out) {
    int wv   = (blockIdx.x * blockDim.x + threadIdx.x) >> 6;  // node id
    int lane = threadIdx.x & 63;
    if (wv >= N_NODES) return;

    const int beg = offsets[wv];
    const int end = offsets[wv + 1];
    const int h   = lane >> 4;
    const size_t foff = (size_t)lane * 4;

    float4 acc = make_float4(0.f, 0.f, 0.f, 0.f);
    float dsum = 0.f;

    const int n4 = (end - beg) >> 2;   // full 4-edge blocks
    int u0, u1, u2, u3;
    if (n4 > 0) {
        const int* sp = srcs + beg;
        u0 = sp[0]; u1 = sp[1]; u2 = sp[2]; u3 = sp[3];
        for (int b = 0; b < n4; b++) {
            const int base = beg + b * 4;
            // preload next block's indices (breaks the idx->gather chain)
            int v0 = 0, v1 = 0, v2 = 0, v3 = 0;
            if (b + 1 < n4) {
                const int* np = srcs + base + 4;
                v0 = np[0]; v1 = np[1]; v2 = np[2]; v3 = np[3];
            }
            // 4 independent 512B gathers in flight
            ushort4 f0 = *(const ushort4*)(ftb + (size_t)u0 * HD + foff);
            ushort4 f1 = *(const ushort4*)(ftb + (size_t)u1 * HD + foff);
            ushort4 f2 = *(const ushort4*)(ftb + (size_t)u2 * HD + foff);
            ushort4 f3 = *(const ushort4*)(ftb + (size_t)u3 * HD + foff);
            float w0 = w4s[(size_t)(base + 0) * NH + h];
            float w1 = w4s[(size_t)(base + 1) * NH + h];
            float w2 = w4s[(size_t)(base + 2) * NH + h];
            float w3 = w4s[(size_t)(base + 3) * NH + h];
            acc.x += w0 * bf2f(f0.x) + w1 * bf2f(f1.x) + w2 * bf2f(f2.x) + w3 * bf2f(f3.x);
            acc.y += w0 * bf2f(f0.y) + w1 * bf2f(f1.y) + w2 * bf2f(f2.y) + w3 * bf2f(f3.y);
            acc.z += w0 * bf2f(f0.z) + w1 * bf2f(f1.z) + w2 * bf2f(f2.z) + w3 * bf2f(f3.z);
            acc.w += w0 * bf2f(f0.w) + w1 * bf2f(f1.w) + w2 * bf2f(f2.w) + w3 * bf2f(f3.w);
            dsum += (w0 + w1) + (w2 + w3);
            u0 = v0; u1 = v1; u2 = v2; u3 = v3;
        }
    }
    // tail (0..3 edges)
    for (int p = beg + n4 * 4; p < end; p++) {
        int u = srcs[p];
        float w = w4s[(size_t)p * NH + h];
        ushort4 f = *(const ushort4*)(ftb + (size_t)u * HD + foff);
        acc.x += w * bf2f(f.x);
        acc.y += w * bf2f(f.y);
        acc.z += w * bf2f(f.z);
        acc.w += w * bf2f(f.w);
        dsum += w;
    }

    float inv = (dsum > 0.f) ? (1.f / dsum) : 0.f;
    acc.x *= inv; acc.y *= inv; acc.z *= inv; acc.w *= inv;
    *(float4*)(out + (size_t)wv * HD + foff) = acc;
}

// ---------------- launch ----------------
extern "C" void kernel_launch(void* const* d_in, const int* in_sizes, int n_in,
                              void* d_out, int out_size, void* d_ws, size_t ws_size,
                              hipStream_t stream) {
    const float* feat   = (const float*)d_in[0];
    const float* W      = (const float*)d_in[1];
    const float* attn_l = (const float*)d_in[2];
    const float* attn_r = (const float*)d_in[3];
    const int*   src    = (const int*)d_in[4];
    const int*   dst    = (const int*)d_in[5];
    float* out = (float*)d_out;

    char* p = (char*)d_ws;
    auto alloc = [&](size_t bytes) -> char* {
        char* r = p;
        p += (bytes + 255) & ~(size_t)255;
        return r;
    };
    unsigned short* ftb     = (unsigned short*)alloc((size_t)N_NODES * HD * 2); // 25.6 MB
    unsigned short* Wtb     = (unsigned short*)alloc((size_t)IN_F * HD * 2);
    float*          el      = (float*)alloc((size_t)N_NODES * NH * 4);
    float*          er      = (float*)alloc((size_t)N_NODES * NH * 4);
    float*          w4s     = (float*)alloc((size_t)N_EDGES * NH * 4);   // 12.8 MB
    int*            srcs    = (int*)alloc((size_t)N_EDGES * 4);          // 3.2 MB
    int*            counts  = (int*)alloc((size_t)N_NODES * 4);
    int*            offsets = (int*)alloc((size_t)(N_NODES + 1) * 4);
    int*            cursor  = (int*)alloc((size_t)N_NODES * 4);
    int*            bsums   = (int*)alloc((size_t)NB * 4);
    int*            boffs   = (int*)alloc((size_t)NB * 4);

    // 1. setup: zero counts + W -> Wt bf16 (one launch)
    setup_kernel<<<NB + (IN_F * HD + 255) / 256, 256, 0, stream>>>(W, Wtb, counts);
    // 2. per-dst counts
    count_kernel<<<(N_EDGES + 255) / 256, 256, 0, stream>>>(dst, counts);
    // 3. ftb = bf16(feat @ W) + fused el/er (64x256 tile, single A pass)
    gemm_kernel<<<(N_NODES + 63) / 64, 256, 0, stream>>>(feat, Wtb, attn_l, attn_r,
                                                         ftb, el, er);
    // 4. parallel 3-phase scan -> offsets, cursor
    partial_kernel<<<NB, 256, 0, stream>>>(counts, bsums);
    bscan_kernel<<<1, 256, 0, stream>>>(bsums, boffs);
    scatter_scan_kernel<<<NB, 256, 0, stream>>>(counts, boffs, offsets, cursor);
    // 5. edge scores placed in CSR order
    edge_place_kernel<<<(N_EDGES + 255) / 256, 256, 0, stream>>>(src, dst, el, er,
                                                                 cursor, srcs, w4s);
    // 6. aggregate per destination node (normalization fused)
    agg_kernel<<<(N_NODES + 3) / 4, 256, 0, stream>>>(ftb, w4s, srcs, offsets, out);
}